// Round 1
// baseline (1147.877 us; speedup 1.0000x reference)
//
#include <hip/hip_runtime.h>

#define NT 150      // trees
#define NPT 341     // nodes per tree
#define LEAF0 85    // first leaf local index
#define NL (NT*256) // 38400 leaves
#define NN (NT*NPT) // 51150 nodes

__device__ __forceinline__ float sigf(float x){ return 1.0f/(1.0f+__expf(-x)); }

// ---------------- embed: A[leaf][256] = mean over 8 subtokens ----------------
__global__ __launch_bounds__(256) void embed_k(const int* __restrict__ feat,
    const float* __restrict__ emb, float* __restrict__ A){
  int leaf = blockIdx.x;
  int t = threadIdx.x;
  int tree = leaf >> 8;
  long node = (long)tree*NPT + LEAF0 + (leaf & 255);
  const int* f = feat + node*8;
  float s = 0.f;
  #pragma unroll
  for (int j=0;j<8;j++) s += emb[(long)f[j]*256 + t];
  A[(long)leaf*256 + t] = s*0.125f;
}

// ---------------- leaf GEMM: iou = A@W_iou + b; -> h,c at leaf nodes --------
// tile: 64 rows x 64 hid-cols (x3 gates). threads 16x16, 4x4(x3) acc each.
__global__ __launch_bounds__(256) void leaf_gemm(const float* __restrict__ A,
    const float* __restrict__ W, const float* __restrict__ b,
    float* __restrict__ h, float* __restrict__ c){
  __shared__ float As[16][68];    // [k][row]
  __shared__ float Bs[16][192];   // [k][gate*64+col]
  int tid = threadIdx.x;
  int tx = tid & 15, ty = tid >> 4;
  int rowbase = blockIdx.x * 64;
  int colbase = blockIdx.y * 64;

  float acc[3][4][4];
  #pragma unroll
  for (int g=0;g<3;g++)
    #pragma unroll
    for (int i=0;i<4;i++)
      #pragma unroll
      for (int q=0;q<4;q++) acc[g][i][q]=0.f;

  int ciL = tid >> 2, w4 = tid & 3;
  const float* arow = A + (long)(rowbase+ciL)*256 + w4*4;

  for (int k0=0;k0<256;k0+=16){
    float4 av = *(const float4*)&arow[k0];
    As[w4*4+0][ciL]=av.x; As[w4*4+1][ciL]=av.y; As[w4*4+2][ciL]=av.z; As[w4*4+3][ciL]=av.w;
    #pragma unroll
    for (int g=0;g<3;g++){
      #pragma unroll
      for (int i=0;i<4;i++){
        int e = tid + 256*i; int kk = e>>6, j = e&63;
        Bs[kk][g*64+j] = W[(long)(k0+kk)*768 + g*256 + colbase + j];
      }
    }
    __syncthreads();
    #pragma unroll
    for (int kk=0;kk<16;kk++){
      float4 a4 = *(const float4*)&As[kk][ty*4];
      float ar[4] = {a4.x,a4.y,a4.z,a4.w};
      #pragma unroll
      for (int g=0;g<3;g++){
        float4 b4 = *(const float4*)&Bs[kk][g*64 + tx*4];
        float br[4] = {b4.x,b4.y,b4.z,b4.w};
        #pragma unroll
        for (int i=0;i<4;i++)
          #pragma unroll
          for (int q=0;q<4;q++) acc[g][i][q] += ar[i]*br[q];
      }
    }
    __syncthreads();
  }
  #pragma unroll
  for (int i=0;i<4;i++){
    int leaf = rowbase + ty*4 + i;
    int tree = leaf >> 8;
    long node = (long)tree*NPT + LEAF0 + (leaf & 255);
    float hv[4], cv[4];
    #pragma unroll
    for (int q=0;q<4;q++){
      int hc = colbase + tx*4 + q;
      float ii = acc[0][i][q] + b[hc];
      float oo = acc[1][i][q] + b[256+hc];
      float uu = acc[2][i][q] + b[512+hc];
      float cc = sigf(ii)*tanhf(uu);
      cv[q] = cc;
      hv[q] = sigf(oo)*tanhf(cc);
    }
    long off = node*256 + colbase + tx*4;
    *(float4*)&h[off] = make_float4(hv[0],hv[1],hv[2],hv[3]);
    *(float4*)&c[off] = make_float4(cv[0],cv[1],cv[2],cv[3]);
  }
}

// ---------------- internal level: 16 nodes x 64 hid per block ---------------
// forget: [64 children,256]@UfW[:,64]; iou: h_tild[16,256]@U_iou[:,3x64]
__global__ __launch_bounds__(256) void level_k(
    const float* __restrict__ Uiou, const float* __restrict__ UfW,
    const float* __restrict__ Ufb, const float* __restrict__ biou,
    float* __restrict__ h, float* __restrict__ c,
    int M, int shift, int base){
  __shared__ float Ch[16][68];    // [k][child 0..63]
  __shared__ float Ht[16][17];    // [k][node 0..15]
  __shared__ float UfWs[16][64];
  __shared__ float Us[16][192];
  int tid = threadIdx.x;
  int tx = tid & 15, ty = tid >> 4;
  int colbase = blockIdx.y * 64;
  int mbase = blockIdx.x * 16;
  int mask = (1<<shift)-1;

  // loader mapping: child ciL of node mbase+(ciL>>2)
  int ciL = tid >> 2, w4 = tid & 3;
  int mL = mbase + (ciL >> 2); if (mL > M-1) mL = M-1;
  int treeL = mL >> shift;
  int localL = base + (mL & mask);
  long cnL = (long)treeL*NPT + 4*localL + 1 + (ciL & 3);
  const float* hrow = h + cnL*256 + w4*4;

  float accf[4][4];   // child i of node ty x fcol q
  float acci[3][4];   // node ty: gate g x col q
  #pragma unroll
  for (int i=0;i<4;i++)
    #pragma unroll
    for (int q=0;q<4;q++) accf[i][q]=0.f;
  #pragma unroll
  for (int g=0;g<3;g++)
    #pragma unroll
    for (int q=0;q<4;q++) acci[g][q]=0.f;

  for (int k0=0;k0<256;k0+=16){
    float4 hvv = *(const float4*)&hrow[k0];
    Ch[w4*4+0][ciL]=hvv.x; Ch[w4*4+1][ciL]=hvv.y; Ch[w4*4+2][ciL]=hvv.z; Ch[w4*4+3][ciL]=hvv.w;
    #pragma unroll
    for (int i=0;i<4;i++){
      int e = tid + 256*i; int kk = e>>6, j = e&63;
      UfWs[kk][j] = UfW[(long)(k0+kk)*256 + colbase + j];
    }
    #pragma unroll
    for (int g=0;g<3;g++){
      #pragma unroll
      for (int i=0;i<4;i++){
        int e = tid + 256*i; int kk = e>>6, j = e&63;
        Us[kk][g*64+j] = Uiou[(long)(k0+kk)*768 + g*256 + colbase + j];
      }
    }
    __syncthreads();
    {
      int kk = tid >> 4, n = tid & 15;
      Ht[kk][n] = Ch[kk][4*n+0]+Ch[kk][4*n+1]+Ch[kk][4*n+2]+Ch[kk][4*n+3];
    }
    __syncthreads();
    #pragma unroll
    for (int kk=0;kk<16;kk++){
      float4 a4 = *(const float4*)&Ch[kk][ty*4];
      float ar[4] = {a4.x,a4.y,a4.z,a4.w};
      float at = Ht[kk][ty];
      float4 bf4 = *(const float4*)&UfWs[kk][tx*4];
      float br[4] = {bf4.x,bf4.y,bf4.z,bf4.w};
      #pragma unroll
      for (int i=0;i<4;i++)
        #pragma unroll
        for (int q=0;q<4;q++) accf[i][q] += ar[i]*br[q];
      #pragma unroll
      for (int g=0;g<3;g++){
        float4 b4 = *(const float4*)&Us[kk][g*64 + tx*4];
        acci[g][0] += at*b4.x; acci[g][1] += at*b4.y;
        acci[g][2] += at*b4.z; acci[g][3] += at*b4.w;
      }
    }
    __syncthreads();
  }

  int m = mbase + ty;
  int mm = m < M ? m : M-1;
  int tree = mm >> shift;
  int local = base + (mm & mask);
  long node = (long)tree*NPT + local;
  int hc0 = colbase + tx*4;
  float csum[4] = {0.f,0.f,0.f,0.f};
  #pragma unroll
  for (int i=0;i<4;i++){
    long cn = (long)tree*NPT + 4*local + 1 + i;
    float4 cvv = *(const float4*)&c[cn*256 + hc0];
    float cvr[4] = {cvv.x,cvv.y,cvv.z,cvv.w};
    #pragma unroll
    for (int q=0;q<4;q++){
      float fg = sigf(accf[i][q] + Ufb[hc0+q]);
      csum[q] += fg*cvr[q];
    }
  }
  float hv[4], cv[4];
  #pragma unroll
  for (int q=0;q<4;q++){
    float ii = acci[0][q] + biou[hc0+q];
    float oo = acci[1][q] + biou[256+hc0+q];
    float uu = acci[2][q] + biou[512+hc0+q];
    float cc = sigf(ii)*tanhf(uu) + csum[q];
    cv[q] = cc;
    hv[q] = sigf(oo)*tanhf(cc);
  }
  if (m < M){
    long off = node*256 + hc0;
    *(float4*)&h[off] = make_float4(hv[0],hv[1],hv[2],hv[3]);
    *(float4*)&c[off] = make_float4(cv[0],cv[1],cv[2],cv[3]);
  }
}

// ---------------- readout: relu(mean over 341 nodes) ------------------------
__global__ __launch_bounds__(256) void readout_k(const float* __restrict__ h,
    float* __restrict__ mo){
  int tree = blockIdx.x; int t = threadIdx.x;
  const float* hp = h + (long)tree*NPT*256 + t;
  float s0=0.f,s1=0.f,s2=0.f,s3=0.f;
  for (int i=0; i<340; i+=4){
    s0 += hp[(long)(i+0)*256]; s1 += hp[(long)(i+1)*256];
    s2 += hp[(long)(i+2)*256]; s3 += hp[(long)(i+3)*256];
  }
  float s = s0+s1+s2+s3 + hp[(long)340*256];
  mo[tree*256+t] = fmaxf(s*(1.0f/341.0f), 0.f);
}

// ---------------- final: leaky_relu(concat@Wf + bf) -> softmax --------------
__global__ __launch_bounds__(64) void final_k(const float* __restrict__ m1,
    const float* __restrict__ m2, const float* __restrict__ Wf,
    const float* __restrict__ bf, float* __restrict__ out){
  int tree = blockIdx.x; int t = threadIdx.x;
  float p0=0.f, p1=0.f;
  for (int k=t;k<512;k+=64){
    float x = (k<256) ? m1[tree*256+k] : m2[tree*256+(k-256)];
    p0 += x*Wf[k*2+0]; p1 += x*Wf[k*2+1];
  }
  #pragma unroll
  for (int off=32; off>0; off>>=1){
    p0 += __shfl_down(p0, off);
    p1 += __shfl_down(p1, off);
  }
  if (t==0){
    float l0 = p0+bf[0], l1 = p1+bf[1];
    l0 = (l0>0.f)?l0:0.01f*l0;
    l1 = (l1>0.f)?l1:0.01f*l1;
    float mx = fmaxf(l0,l1);
    float e0 = __expf(l0-mx), e1 = __expf(l1-mx);
    float inv = 1.0f/(e0+e1);
    out[tree*2+0] = e0*inv; out[tree*2+1] = e1*inv;
  }
}

extern "C" void kernel_launch(void* const* d_in, const int* in_sizes, int n_in,
                              void* d_out, int out_size, void* d_ws, size_t ws_size,
                              hipStream_t stream) {
  const int*   feat1 = (const int*)  d_in[0];
  const int*   feat2 = (const int*)  d_in[1];
  const float* emb1  = (const float*)d_in[2];
  const float* emb2  = (const float*)d_in[3];
  const float* Wiou1 = (const float*)d_in[4];
  const float* Wiou2 = (const float*)d_in[5];
  const float* Uiou1 = (const float*)d_in[6];
  const float* Uiou2 = (const float*)d_in[7];
  const float* UfW1  = (const float*)d_in[8];
  const float* Ufb1  = (const float*)d_in[9];
  const float* UfW2  = (const float*)d_in[10];
  const float* Ufb2  = (const float*)d_in[11];
  const float* biou1 = (const float*)d_in[12];
  const float* biou2 = (const float*)d_in[13];
  const float* Wf    = (const float*)d_in[14];
  const float* bfv   = (const float*)d_in[15];
  float* out = (float*)d_out;

  float* ws = (float*)d_ws;
  float* h  = ws;                       // NN*256
  float* c  = h  + (size_t)NN*256;      // NN*256
  float* A  = c  + (size_t)NN*256;      // NL*256
  float* m1 = A  + (size_t)NL*256;      // 150*256
  float* m2 = m1 + (size_t)NT*256;

  const int   lvlM[4]     = {9600, 2400, 600, 150};
  const int   lvlShift[4] = {6, 4, 2, 0};
  const int   lvlBase[4]  = {21, 5, 1, 0};

  for (int br=0; br<2; br++){
    const int*   feat = br ? feat2 : feat1;
    const float* emb  = br ? emb2  : emb1;
    const float* Wiou = br ? Wiou2 : Wiou1;
    const float* Uiou = br ? Uiou2 : Uiou1;
    const float* UfW  = br ? UfW2  : UfW1;
    const float* Ufb  = br ? Ufb2  : Ufb1;
    const float* biou = br ? biou2 : biou1;
    float* mo = br ? m2 : m1;

    embed_k<<<NL, 256, 0, stream>>>(feat, emb, A);
    leaf_gemm<<<dim3(NL/64, 4), 256, 0, stream>>>(A, Wiou, biou, h, c);
    for (int l=0;l<4;l++){
      int gx = (lvlM[l] + 15)/16;
      level_k<<<dim3(gx, 4), 256, 0, stream>>>(Uiou, UfW, Ufb, biou, h, c,
                                               lvlM[l], lvlShift[l], lvlBase[l]);
    }
    readout_k<<<NT, 256, 0, stream>>>(h, mo);
  }
  final_k<<<NT, 64, 0, stream>>>(m1, m2, Wf, bfv, out);
}

// Round 2
// 471.185 us; speedup vs baseline: 2.4361x; 2.4361x over previous
//
#include <hip/hip_runtime.h>

#define NT 150      // trees
#define NPT 341     // nodes per tree
#define LEAF0 85    // first leaf local index
#define NL (NT*256) // 38400 leaves
#define NN (NT*NPT) // 51150 nodes

typedef __attribute__((ext_vector_type(8))) short short8;
typedef __attribute__((ext_vector_type(4))) float floatx4;

__device__ __forceinline__ float sigf(float x){ return 1.0f/(1.0f+__expf(-x)); }
__device__ __forceinline__ float bf2f(ushort u){ union{unsigned i; float f;} v; v.i = ((unsigned)u)<<16; return v.f; }
__device__ __forceinline__ ushort f2bf(float x){ union{float f; unsigned i;} v; v.f = x; unsigned r = (v.i + 0x7fff + ((v.i>>16)&1))>>16; return (ushort)r; }

// ---------- transpose+convert: src fp32 [256][N] -> dst bf16 [N][256] -------
__global__ __launch_bounds__(256) void conv_k(
    const float* __restrict__ W1, const float* __restrict__ U1, const float* __restrict__ F1,
    const float* __restrict__ W2, const float* __restrict__ U2, const float* __restrict__ F2,
    ushort* Wt1, ushort* Ut1, ushort* Ft1, ushort* Wt2, ushort* Ut2, ushort* Ft2){
  __shared__ float T[32][33];
  const float* src; ushort* dst; int N;
  switch (blockIdx.z){
    case 0: src=W1; dst=Wt1; N=768; break;
    case 1: src=U1; dst=Ut1; N=768; break;
    case 2: src=F1; dst=Ft1; N=256; break;
    case 3: src=W2; dst=Wt2; N=768; break;
    case 4: src=U2; dst=Ut2; N=768; break;
    default: src=F2; dst=Ft2; N=256; break;
  }
  int n0 = blockIdx.x*32; if (n0 >= N) return;
  int k0 = blockIdx.y*32;
  int nl = threadIdx.x & 31, kb = threadIdx.x >> 5;
  #pragma unroll
  for (int i=0;i<4;i++){ int kk = kb*4+i; T[kk][nl] = src[(size_t)(k0+kk)*N + n0 + nl]; }
  __syncthreads();
  #pragma unroll
  for (int i=0;i<4;i++){ int nn = kb*4+i; dst[(size_t)(n0+nn)*256 + k0 + nl] = f2bf(T[nl][nn]); }
}

// ---------------- embed: A[leaf][256] = mean over 8 subtokens (bf16) --------
__global__ __launch_bounds__(256) void embed_k(
    const int* __restrict__ f1, const int* __restrict__ f2,
    const float* __restrict__ e1, const float* __restrict__ e2,
    ushort* __restrict__ A1, ushort* __restrict__ A2){
  int br = blockIdx.y;
  const int* feat = br ? f2 : f1;
  const float* emb = br ? e2 : e1;
  ushort* A = br ? A2 : A1;
  int leaf = blockIdx.x;
  int t = threadIdx.x;
  int tree = leaf >> 8;
  size_t node = (size_t)tree*NPT + LEAF0 + (leaf & 255);
  const int* f = feat + node*8;
  float s = 0.f;
  #pragma unroll
  for (int j=0;j<8;j++) s += emb[(size_t)f[j]*256 + t];
  A[(size_t)leaf*256 + t] = f2bf(s*0.125f);
}

// ---------------- leaf GEMM via MFMA: 64 rows x (3 gates x 64 hid) ----------
__global__ __launch_bounds__(256) void leaf_gemm(
    const ushort* __restrict__ A, const ushort* __restrict__ Wt,
    const float* __restrict__ biou, ushort* __restrict__ h, float* __restrict__ c){
  __shared__ __attribute__((aligned(16))) ushort As[64*40];
  int tid = threadIdx.x;
  int lane = tid & 63, wav = tid >> 6, quad = lane >> 4, l15 = lane & 15;
  int rowbase = blockIdx.x*64, cb = blockIdx.y;

  floatx4 acc[3][4];
  #pragma unroll
  for (int g=0;g<3;g++)
    #pragma unroll
    for (int r=0;r<4;r++) acc[g][r] = (floatx4){0.f,0.f,0.f,0.f};

  int srow = tid >> 2, skc = tid & 3;
  const ushort* agp = A + (size_t)(rowbase+srow)*256 + skc*8;
  const ushort* bp0 = Wt + (size_t)(0*256 + cb*64 + wav*16 + l15)*256 + quad*8;
  const ushort* bp1 = Wt + (size_t)(1*256 + cb*64 + wav*16 + l15)*256 + quad*8;
  const ushort* bp2 = Wt + (size_t)(2*256 + cb*64 + wav*16 + l15)*256 + quad*8;

  for (int k0=0;k0<256;k0+=32){
    __syncthreads();
    *(short8*)&As[srow*40 + skc*8] = *(const short8*)(agp + k0);
    __syncthreads();
    short8 b0 = *(const short8*)(bp0 + k0);
    short8 b1 = *(const short8*)(bp1 + k0);
    short8 b2 = *(const short8*)(bp2 + k0);
    #pragma unroll
    for (int r=0;r<4;r++){
      short8 a = *(const short8*)&As[(16*r + l15)*40 + quad*8];
      acc[0][r] = __builtin_amdgcn_mfma_f32_16x16x32_bf16(a, b0, acc[0][r], 0,0,0);
      acc[1][r] = __builtin_amdgcn_mfma_f32_16x16x32_bf16(a, b1, acc[1][r], 0,0,0);
      acc[2][r] = __builtin_amdgcn_mfma_f32_16x16x32_bf16(a, b2, acc[2][r], 0,0,0);
    }
  }
  int hc = cb*64 + wav*16 + l15;
  float bi = biou[hc], bo = biou[256+hc], bu = biou[512+hc];
  #pragma unroll
  for (int r=0;r<4;r++){
    #pragma unroll
    for (int reg=0;reg<4;reg++){
      int leaf = rowbase + 16*r + quad*4 + reg;
      int tree = leaf >> 8;
      size_t node = (size_t)tree*NPT + LEAF0 + (leaf & 255);
      float iv = acc[0][r][reg] + bi;
      float ov = acc[1][r][reg] + bo;
      float uv = acc[2][r][reg] + bu;
      float cc = sigf(iv)*tanhf(uv);
      float hh = sigf(ov)*tanhf(cc);
      h[node*256 + hc] = f2bf(hh);
      c[node*256 + hc] = cc;
    }
  }
}

// ---------------- internal level via MFMA: 16 nodes x 64 hid per block ------
__global__ __launch_bounds__(256) void level_k(
    const ushort* __restrict__ Ut, const ushort* __restrict__ Ft,
    const float* __restrict__ Ufb, const float* __restrict__ biou,
    ushort* __restrict__ h, float* __restrict__ c,
    int M, int shift, int base){
  __shared__ __attribute__((aligned(16))) ushort Ch[64*40];
  __shared__ __attribute__((aligned(16))) ushort Ht[16*40];
  __shared__ float Cs[16*68];
  int tid = threadIdx.x;
  int lane = tid & 63, wav = tid >> 6, quad = lane >> 4, l15 = lane & 15;
  int m0 = blockIdx.x*16, cb = blockIdx.y;
  int mask = (1<<shift)-1;

  // staging mapping: thread -> (child 0..63, k-chunk 0..3)
  int cl = tid >> 2, skc = tid & 3;
  int sm = m0 + (cl >> 2); if (sm > M-1) sm = M-1;
  int stree = sm >> shift, sloc = base + (sm & mask);
  const ushort* sgp = h + ((size_t)stree*NPT + 4*sloc + 1 + (cl & 3))*256 + skc*8;

  const ushort* bfp = Ft + (size_t)(cb*64 + wav*16 + l15)*256 + quad*8;
  const ushort* bp0 = Ut + (size_t)(0*256 + cb*64 + wav*16 + l15)*256 + quad*8;
  const ushort* bp1 = Ut + (size_t)(1*256 + cb*64 + wav*16 + l15)*256 + quad*8;
  const ushort* bp2 = Ut + (size_t)(2*256 + cb*64 + wav*16 + l15)*256 + quad*8;

  floatx4 accf[4], acci[3];
  #pragma unroll
  for (int r=0;r<4;r++) accf[r] = (floatx4){0.f,0.f,0.f,0.f};
  #pragma unroll
  for (int g=0;g<3;g++) acci[g] = (floatx4){0.f,0.f,0.f,0.f};

  for (int k0=0;k0<256;k0+=32){
    __syncthreads();
    *(short8*)&Ch[cl*40 + skc*8] = *(const short8*)(sgp + k0);
    __syncthreads();
    if (tid < 64){
      int hn = tid >> 2, hk = (tid & 3)*8;
      short8 r0 = *(const short8*)&Ch[(4*hn+0)*40 + hk];
      short8 r1 = *(const short8*)&Ch[(4*hn+1)*40 + hk];
      short8 r2 = *(const short8*)&Ch[(4*hn+2)*40 + hk];
      short8 r3 = *(const short8*)&Ch[(4*hn+3)*40 + hk];
      short8 o;
      #pragma unroll
      for (int j=0;j<8;j++){
        float s = bf2f((ushort)r0[j]) + bf2f((ushort)r1[j]) + bf2f((ushort)r2[j]) + bf2f((ushort)r3[j]);
        o[j] = (short)f2bf(s);
      }
      *(short8*)&Ht[hn*40 + hk] = o;
    }
    __syncthreads();
    short8 bfw = *(const short8*)(bfp + k0);
    short8 b0 = *(const short8*)(bp0 + k0);
    short8 b1 = *(const short8*)(bp1 + k0);
    short8 b2 = *(const short8*)(bp2 + k0);
    short8 ah = *(const short8*)&Ht[l15*40 + quad*8];
    #pragma unroll
    for (int r=0;r<4;r++){
      short8 a = *(const short8*)&Ch[(16*r + l15)*40 + quad*8];
      accf[r] = __builtin_amdgcn_mfma_f32_16x16x32_bf16(a, bfw, accf[r], 0,0,0);
    }
    acci[0] = __builtin_amdgcn_mfma_f32_16x16x32_bf16(ah, b0, acci[0], 0,0,0);
    acci[1] = __builtin_amdgcn_mfma_f32_16x16x32_bf16(ah, b1, acci[1], 0,0,0);
    acci[2] = __builtin_amdgcn_mfma_f32_16x16x32_bf16(ah, b2, acci[2], 0,0,0);
  }

  int hc = cb*64 + wav*16 + l15;
  float ufb = Ufb[hc];
  #pragma unroll
  for (int r=0;r<4;r++){
    int ni = 4*r + quad;
    int m = m0 + ni; if (m > M-1) m = M-1;
    int tree = m >> shift, loc = base + (m & mask);
    size_t chbase = ((size_t)tree*NPT + 4*loc + 1)*256 + hc;
    float cs = 0.f;
    #pragma unroll
    for (int reg=0;reg<4;reg++)
      cs += sigf(accf[r][reg] + ufb) * c[chbase + (size_t)reg*256];
    Cs[ni*68 + wav*16 + l15] = cs;
  }
  __syncthreads();
  float bi = biou[hc], bo = biou[256+hc], bu = biou[512+hc];
  #pragma unroll
  for (int reg=0;reg<4;reg++){
    int ni = quad*4 + reg;
    int m = m0 + ni;
    if (m < M){
      int tree = m >> shift, loc = base + (m & mask);
      size_t off = ((size_t)tree*NPT + loc)*256 + hc;
      float cs = Cs[ni*68 + wav*16 + l15];
      float iv = acci[0][reg] + bi;
      float ov = acci[1][reg] + bo;
      float uv = acci[2][reg] + bu;
      float cn = sigf(iv)*tanhf(uv) + cs;
      float hn = sigf(ov)*tanhf(cn);
      h[off] = f2bf(hn);
      c[off] = cn;
    }
  }
}

// ---------------- readout: relu(mean over 341 nodes) ------------------------
__global__ __launch_bounds__(256) void readout_k(const ushort* __restrict__ h,
    float* __restrict__ mo){
  int tree = blockIdx.x; int t = threadIdx.x;
  const ushort* hp = h + (size_t)tree*NPT*256 + t;
  float s0=0.f,s1=0.f,s2=0.f,s3=0.f;
  for (int i=0; i<340; i+=4){
    s0 += bf2f(hp[(size_t)(i+0)*256]); s1 += bf2f(hp[(size_t)(i+1)*256]);
    s2 += bf2f(hp[(size_t)(i+2)*256]); s3 += bf2f(hp[(size_t)(i+3)*256]);
  }
  float s = s0+s1+s2+s3 + bf2f(hp[(size_t)340*256]);
  mo[tree*256+t] = fmaxf(s*(1.0f/341.0f), 0.f);
}

// ---------------- final: leaky_relu(concat@Wf + bf) -> softmax --------------
__global__ __launch_bounds__(64) void final_k(const float* __restrict__ m1,
    const float* __restrict__ m2, const float* __restrict__ Wf,
    const float* __restrict__ bf, float* __restrict__ out){
  int tree = blockIdx.x; int t = threadIdx.x;
  float p0=0.f, p1=0.f;
  for (int k=t;k<512;k+=64){
    float x = (k<256) ? m1[tree*256+k] : m2[tree*256+(k-256)];
    p0 += x*Wf[k*2+0]; p1 += x*Wf[k*2+1];
  }
  #pragma unroll
  for (int off=32; off>0; off>>=1){
    p0 += __shfl_down(p0, off);
    p1 += __shfl_down(p1, off);
  }
  if (t==0){
    float l0 = p0+bf[0], l1 = p1+bf[1];
    l0 = (l0>0.f)?l0:0.01f*l0;
    l1 = (l1>0.f)?l1:0.01f*l1;
    float mx = fmaxf(l0,l1);
    float e0 = __expf(l0-mx), e1 = __expf(l1-mx);
    float inv = 1.0f/(e0+e1);
    out[tree*2+0] = e0*inv; out[tree*2+1] = e1*inv;
  }
}

extern "C" void kernel_launch(void* const* d_in, const int* in_sizes, int n_in,
                              void* d_out, int out_size, void* d_ws, size_t ws_size,
                              hipStream_t stream) {
  const int*   feat1 = (const int*)  d_in[0];
  const int*   feat2 = (const int*)  d_in[1];
  const float* emb1  = (const float*)d_in[2];
  const float* emb2  = (const float*)d_in[3];
  const float* Wiou1 = (const float*)d_in[4];
  const float* Wiou2 = (const float*)d_in[5];
  const float* Uiou1 = (const float*)d_in[6];
  const float* Uiou2 = (const float*)d_in[7];
  const float* UfW1  = (const float*)d_in[8];
  const float* Ufb1  = (const float*)d_in[9];
  const float* UfW2  = (const float*)d_in[10];
  const float* Ufb2  = (const float*)d_in[11];
  const float* biou1 = (const float*)d_in[12];
  const float* biou2 = (const float*)d_in[13];
  const float* Wf    = (const float*)d_in[14];
  const float* bfv   = (const float*)d_in[15];
  float* out = (float*)d_out;

  char* ws = (char*)d_ws;
  float*  c   = (float*)ws;                 ws += (size_t)NN*256*4;   // 52.4 MB
  ushort* h   = (ushort*)ws;                ws += (size_t)NN*256*2;   // 26.2 MB
  ushort* A1  = (ushort*)ws;                ws += (size_t)NL*256*2;   // 19.7 MB
  ushort* A2  = (ushort*)ws;                ws += (size_t)NL*256*2;   // 19.7 MB
  ushort* Wt1 = (ushort*)ws;                ws += 768*256*2;
  ushort* Ut1 = (ushort*)ws;                ws += 768*256*2;
  ushort* Ft1 = (ushort*)ws;                ws += 256*256*2;
  ushort* Wt2 = (ushort*)ws;                ws += 768*256*2;
  ushort* Ut2 = (ushort*)ws;                ws += 768*256*2;
  ushort* Ft2 = (ushort*)ws;                ws += 256*256*2;
  float*  m1  = (float*)ws;                 ws += NT*256*4;
  float*  m2  = (float*)ws;                 ws += NT*256*4;

  conv_k<<<dim3(24, 8, 6), 256, 0, stream>>>(Wiou1, Uiou1, UfW1, Wiou2, Uiou2, UfW2,
                                             Wt1, Ut1, Ft1, Wt2, Ut2, Ft2);
  embed_k<<<dim3(NL, 2), 256, 0, stream>>>(feat1, feat2, emb1, emb2, A1, A2);

  const int lvlM[4]     = {9600, 2400, 600, 150};
  const int lvlShift[4] = {6, 4, 2, 0};
  const int lvlBase[4]  = {21, 5, 1, 0};

  for (int br=0; br<2; br++){
    const ushort* A    = br ? A2   : A1;
    const ushort* Wt   = br ? Wt2  : Wt1;
    const ushort* Ut   = br ? Ut2  : Ut1;
    const ushort* Ft   = br ? Ft2  : Ft1;
    const float*  Ufb  = br ? Ufb2 : Ufb1;
    const float*  biou = br ? biou2 : biou1;
    float* mo = br ? m2 : m1;

    leaf_gemm<<<dim3(NL/64, 4), 256, 0, stream>>>(A, Wt, biou, h, c);
    for (int l=0;l<4;l++){
      int gx = (lvlM[l] + 15)/16;
      level_k<<<dim3(gx, 4), 256, 0, stream>>>(Ut, Ft, Ufb, biou, h, c,
                                               lvlM[l], lvlShift[l], lvlBase[l]);
    }
    readout_k<<<NT, 256, 0, stream>>>(h, mo);
  }
  final_k<<<NT, 64, 0, stream>>>(m1, m2, Wf, bfv, out);
}

// Round 3
// 406.339 us; speedup vs baseline: 2.8249x; 1.1596x over previous
//
#include <hip/hip_runtime.h>

#define NT 150      // trees
#define NPT 341     // nodes per tree
#define LEAF0 85    // first leaf local index
#define NL (NT*256) // 38400 leaves
#define NN (NT*NPT) // 51150 nodes
#define VOCAB 10000

typedef __attribute__((ext_vector_type(8))) short short8;
typedef __attribute__((ext_vector_type(4))) float floatx4;

__device__ __forceinline__ float sigf(float x){ return 1.0f/(1.0f+__expf(-x)); }
__device__ __forceinline__ float bf2f(ushort u){ union{unsigned i; float f;} v; v.i = ((unsigned)u)<<16; return v.f; }
__device__ __forceinline__ ushort f2bf(float x){ union{float f; unsigned i;} v; v.f = x; return (ushort)((v.i + 0x7fff + ((v.i>>16)&1))>>16); }

// ---------- weights transpose+convert: fp32 [256][N] -> bf16 [N][256] -------
__global__ __launch_bounds__(256) void convW_k(
    const float* __restrict__ W1, const float* __restrict__ U1, const float* __restrict__ F1,
    const float* __restrict__ W2, const float* __restrict__ U2, const float* __restrict__ F2,
    ushort* Wt1, ushort* Ut1, ushort* Ft1, ushort* Wt2, ushort* Ut2, ushort* Ft2){
  __shared__ float T[32][33];
  const float* src; ushort* dst; int N;
  switch (blockIdx.z){
    case 0: src=W1; dst=Wt1; N=768; break;
    case 1: src=U1; dst=Ut1; N=768; break;
    case 2: src=F1; dst=Ft1; N=256; break;
    case 3: src=W2; dst=Wt2; N=768; break;
    case 4: src=U2; dst=Ut2; N=768; break;
    default: src=F2; dst=Ft2; N=256; break;
  }
  int n0 = blockIdx.x*32; if (n0 >= N) return;
  int k0 = blockIdx.y*32;
  int nl = threadIdx.x & 31, kb = threadIdx.x >> 5;
  #pragma unroll
  for (int i=0;i<4;i++){ int kk = kb*4+i; T[kk][nl] = src[(size_t)(k0+kk)*N + n0 + nl]; }
  __syncthreads();
  #pragma unroll
  for (int i=0;i<4;i++){ int nn = kb*4+i; dst[(size_t)(n0+nn)*256 + k0 + nl] = f2bf(T[nl][nn]); }
}

// ---------- embedding tables fp32 -> bf16 (elementwise) ---------------------
__global__ __launch_bounds__(256) void convE_k(
    const float* __restrict__ e1, const float* __restrict__ e2,
    ushort* __restrict__ E1, ushort* __restrict__ E2){
  const float* s = blockIdx.y ? e2 : e1;
  ushort* d = blockIdx.y ? E2 : E1;
  size_t i = ((size_t)blockIdx.x*256 + threadIdx.x)*4;
  float4 v = *(const float4*)&s[i];
  d[i+0]=f2bf(v.x); d[i+1]=f2bf(v.y); d[i+2]=f2bf(v.z); d[i+3]=f2bf(v.w);
}

// ---------- embed: mean of 8 bf16 rows -> h leaf slots (bf16) ---------------
__global__ __launch_bounds__(256) void embed_k(
    const int* __restrict__ f1, const int* __restrict__ f2,
    const ushort* __restrict__ E1, const ushort* __restrict__ E2,
    ushort* __restrict__ h1, ushort* __restrict__ h2){
  int br = blockIdx.y;
  const int* feat = br ? f2 : f1;
  const ushort* E = br ? E2 : E1;
  ushort* h = br ? h2 : h1;
  int t = threadIdx.x;
  int leaf = blockIdx.x*16 + (t>>4);
  int seg = t & 15;
  int tree = leaf >> 8;
  size_t node = (size_t)tree*NPT + LEAF0 + (leaf & 255);
  const int* f = feat + node*8;
  float s[16];
  #pragma unroll
  for (int q=0;q<16;q++) s[q]=0.f;
  #pragma unroll
  for (int j=0;j<8;j++){
    const ushort* row = E + (size_t)f[j]*256 + seg*16;
    short8 a = *(const short8*)row;
    short8 b = *(const short8*)(row+8);
    #pragma unroll
    for (int q=0;q<8;q++){ s[q]+=bf2f((ushort)a[q]); s[8+q]+=bf2f((ushort)b[q]); }
  }
  short8 o1, o2;
  #pragma unroll
  for (int q=0;q<8;q++){ o1[q]=(short)f2bf(s[q]*0.125f); o2[q]=(short)f2bf(s[8+q]*0.125f); }
  ushort* dst = h + node*256 + seg*16;
  *(short8*)dst = o1; *(short8*)(dst+8) = o2;
}

// ---------- leaf GEMM: 64 leaves x all 768 outputs, 1024 threads ------------
// reads pooled embeds from h leaf slots (full prestage), overwrites h,c.
__global__ __launch_bounds__(1024) void leaf_gemm(
    const ushort* __restrict__ Wt1, const float* __restrict__ b1,
    const ushort* __restrict__ Wt2, const float* __restrict__ b2,
    ushort* __restrict__ h1, ushort* __restrict__ c1,
    ushort* __restrict__ h2, ushort* __restrict__ c2){
  __shared__ __attribute__((aligned(16))) ushort As[8][64*40];
  int br = blockIdx.y;
  const ushort* Wt = br ? Wt2 : Wt1;
  const float* biou = br ? b2 : b1;
  ushort* h = br ? h2 : h1;
  ushort* c = br ? c2 : c1;
  int tid = threadIdx.x;
  int lane = tid & 63, wav = tid >> 6, quad = lane >> 4, l15 = lane & 15;
  int rowbase = blockIdx.x*64;

  { // stage full 64x256 A tile, one barrier
    int row = tid >> 4, seg = tid & 15;
    int leaf = rowbase + row;
    int tree = leaf >> 8;
    size_t node = (size_t)tree*NPT + LEAF0 + (leaf & 255);
    const ushort* src = h + node*256 + seg*16;
    short8 a = *(const short8*)src;
    short8 b = *(const short8*)(src+8);
    int cch = seg >> 1, off = (seg & 1)*16;
    *(short8*)&As[cch][row*40 + off]     = a;
    *(short8*)&As[cch][row*40 + off + 8] = b;
  }
  __syncthreads();

  floatx4 acc[3][4];
  #pragma unroll
  for (int g=0;g<3;g++)
    #pragma unroll
    for (int r=0;r<4;r++) acc[g][r] = (floatx4){0.f,0.f,0.f,0.f};

  const ushort* bp0 = Wt + (size_t)(0*256 + wav*16 + l15)*256 + quad*8;
  const ushort* bp1 = Wt + (size_t)(1*256 + wav*16 + l15)*256 + quad*8;
  const ushort* bp2 = Wt + (size_t)(2*256 + wav*16 + l15)*256 + quad*8;

  #pragma unroll
  for (int cch=0; cch<8; cch++){
    short8 b0 = *(const short8*)(bp0 + cch*32);
    short8 b1 = *(const short8*)(bp1 + cch*32);
    short8 b2 = *(const short8*)(bp2 + cch*32);
    #pragma unroll
    for (int r=0;r<4;r++){
      short8 a = *(const short8*)&As[cch][(16*r + l15)*40 + quad*8];
      acc[0][r] = __builtin_amdgcn_mfma_f32_16x16x32_bf16(a, b0, acc[0][r], 0,0,0);
      acc[1][r] = __builtin_amdgcn_mfma_f32_16x16x32_bf16(a, b1, acc[1][r], 0,0,0);
      acc[2][r] = __builtin_amdgcn_mfma_f32_16x16x32_bf16(a, b2, acc[2][r], 0,0,0);
    }
  }
  int hc = wav*16 + l15;
  float bi = biou[hc], bo = biou[256+hc], bu = biou[512+hc];
  #pragma unroll
  for (int r=0;r<4;r++){
    #pragma unroll
    for (int reg=0;reg<4;reg++){
      int leaf = rowbase + 16*r + quad*4 + reg;
      int tree = leaf >> 8;
      size_t node = (size_t)tree*NPT + LEAF0 + (leaf & 255);
      float iv = acc[0][r][reg] + bi;
      float ov = acc[1][r][reg] + bo;
      float uv = acc[2][r][reg] + bu;
      float cc = sigf(iv)*tanhf(uv);
      float hh = sigf(ov)*tanhf(cc);
      h[node*256 + hc] = f2bf(hh);
      c[node*256 + hc] = f2bf(cc);
    }
  }
}

// ---------- internal level: 16 nodes x 64 hid per block, full prestage ------
__global__ __launch_bounds__(256) void level_k(
    const ushort* __restrict__ Ut1, const ushort* __restrict__ Ft1,
    const float* __restrict__ Ufb1, const float* __restrict__ bi1,
    const ushort* __restrict__ Ut2, const ushort* __restrict__ Ft2,
    const float* __restrict__ Ufb2, const float* __restrict__ bi2,
    ushort* __restrict__ h1, ushort* __restrict__ c1,
    ushort* __restrict__ h2, ushort* __restrict__ c2,
    int M, int shift, int base){
  __shared__ __attribute__((aligned(16))) ushort Ch[8][64*40];
  __shared__ __attribute__((aligned(16))) ushort Ht[8][16*40];
  __shared__ float Cs[16*68];
  int br = blockIdx.z;
  const ushort* Ut = br ? Ut2 : Ut1;
  const ushort* Ft = br ? Ft2 : Ft1;
  const float* Ufb = br ? Ufb2 : Ufb1;
  const float* biou = br ? bi2 : bi1;
  ushort* h = br ? h2 : h1;
  ushort* c = br ? c2 : c1;
  int tid = threadIdx.x;
  int lane = tid & 63, wav = tid >> 6, quad = lane >> 4, l15 = lane & 15;
  int m0 = blockIdx.x*16, cb = blockIdx.y;
  int mask = (1<<shift)-1;

  { // stage all 64 children rows x 256 k
    int cl = tid >> 2, q4 = tid & 3;
    int sm = m0 + (cl >> 2); if (sm > M-1) sm = M-1;
    int stree = sm >> shift, sloc = base + (sm & mask);
    const ushort* sgp = h + ((size_t)stree*NPT + 4*sloc + 1 + (cl & 3))*256 + q4*8;
    #pragma unroll
    for (int cc=0;cc<8;cc++)
      *(short8*)&Ch[cc][cl*40 + q4*8] = *(const short8*)(sgp + cc*32);
  }
  __syncthreads();
  { // h_tild = sum of 4 children, bf16, all chunks
    int n = tid & 15, hcki = tid >> 4;
    int cc = hcki >> 1, off = (hcki & 1)*16;
    float s[16];
    #pragma unroll
    for (int q=0;q<16;q++) s[q]=0.f;
    #pragma unroll
    for (int i=0;i<4;i++){
      short8 a = *(const short8*)&Ch[cc][(4*n+i)*40 + off];
      short8 b = *(const short8*)&Ch[cc][(4*n+i)*40 + off + 8];
      #pragma unroll
      for (int q=0;q<8;q++){ s[q]+=bf2f((ushort)a[q]); s[8+q]+=bf2f((ushort)b[q]); }
    }
    short8 o1,o2;
    #pragma unroll
    for (int q=0;q<8;q++){ o1[q]=(short)f2bf(s[q]); o2[q]=(short)f2bf(s[8+q]); }
    *(short8*)&Ht[cc][n*40 + off]     = o1;
    *(short8*)&Ht[cc][n*40 + off + 8] = o2;
  }
  __syncthreads();

  const ushort* bfp = Ft + (size_t)(cb*64 + wav*16 + l15)*256 + quad*8;
  const ushort* bp0 = Ut + (size_t)(0*256 + cb*64 + wav*16 + l15)*256 + quad*8;
  const ushort* bp1 = Ut + (size_t)(1*256 + cb*64 + wav*16 + l15)*256 + quad*8;
  const ushort* bp2 = Ut + (size_t)(2*256 + cb*64 + wav*16 + l15)*256 + quad*8;

  floatx4 accf[4], acci[3];
  #pragma unroll
  for (int r=0;r<4;r++) accf[r] = (floatx4){0.f,0.f,0.f,0.f};
  #pragma unroll
  for (int g=0;g<3;g++) acci[g] = (floatx4){0.f,0.f,0.f,0.f};

  #pragma unroll
  for (int cc=0; cc<8; cc++){
    short8 bfw = *(const short8*)(bfp + cc*32);
    short8 b0 = *(const short8*)(bp0 + cc*32);
    short8 b1 = *(const short8*)(bp1 + cc*32);
    short8 b2 = *(const short8*)(bp2 + cc*32);
    short8 ah = *(const short8*)&Ht[cc][l15*40 + quad*8];
    #pragma unroll
    for (int r=0;r<4;r++){
      short8 a = *(const short8*)&Ch[cc][(16*r + l15)*40 + quad*8];
      accf[r] = __builtin_amdgcn_mfma_f32_16x16x32_bf16(a, bfw, accf[r], 0,0,0);
    }
    acci[0] = __builtin_amdgcn_mfma_f32_16x16x32_bf16(ah, b0, acci[0], 0,0,0);
    acci[1] = __builtin_amdgcn_mfma_f32_16x16x32_bf16(ah, b1, acci[1], 0,0,0);
    acci[2] = __builtin_amdgcn_mfma_f32_16x16x32_bf16(ah, b2, acci[2], 0,0,0);
  }

  int hc = cb*64 + wav*16 + l15;
  float ufb = Ufb[hc];
  #pragma unroll
  for (int r=0;r<4;r++){
    int ni = 4*r + quad;
    int m = m0 + ni; if (m > M-1) m = M-1;
    int tree = m >> shift, loc = base + (m & mask);
    size_t chbase = ((size_t)tree*NPT + 4*loc + 1)*256 + hc;
    float cs = 0.f;
    #pragma unroll
    for (int reg=0;reg<4;reg++)
      cs += sigf(accf[r][reg] + ufb) * bf2f(c[chbase + (size_t)reg*256]);
    Cs[ni*68 + wav*16 + l15] = cs;
  }
  __syncthreads();
  float bi = biou[hc], bo = biou[256+hc], bu = biou[512+hc];
  #pragma unroll
  for (int reg=0;reg<4;reg++){
    int ni = quad*4 + reg;
    int m = m0 + ni;
    if (m < M){
      int tree = m >> shift, loc = base + (m & mask);
      size_t off = ((size_t)tree*NPT + loc)*256 + hc;
      float cs = Cs[ni*68 + wav*16 + l15];
      float iv = acci[0][reg] + bi;
      float ov = acci[1][reg] + bo;
      float uv = acci[2][reg] + bu;
      float cn = sigf(iv)*tanhf(uv) + cs;
      float hn = sigf(ov)*tanhf(cn);
      h[off] = f2bf(hn);
      c[off] = f2bf(cn);
    }
  }
}

// ---------- readout: relu(mean over 341 nodes) ------------------------------
__global__ __launch_bounds__(256) void readout_k(
    const ushort* __restrict__ h1, const ushort* __restrict__ h2,
    float* __restrict__ m1, float* __restrict__ m2){
  int br = blockIdx.y;
  const ushort* h = br ? h2 : h1;
  float* mo = br ? m2 : m1;
  int tree = blockIdx.x; int t = threadIdx.x;
  const ushort* hp = h + (size_t)tree*NPT*256 + t;
  float s0=0.f,s1=0.f,s2=0.f,s3=0.f;
  for (int i=0; i<340; i+=4){
    s0 += bf2f(hp[(size_t)(i+0)*256]); s1 += bf2f(hp[(size_t)(i+1)*256]);
    s2 += bf2f(hp[(size_t)(i+2)*256]); s3 += bf2f(hp[(size_t)(i+3)*256]);
  }
  float s = s0+s1+s2+s3 + bf2f(hp[(size_t)340*256]);
  mo[tree*256+t] = fmaxf(s*(1.0f/341.0f), 0.f);
}

// ---------- final: leaky_relu(concat@Wf + bf) -> softmax --------------------
__global__ __launch_bounds__(64) void final_k(const float* __restrict__ m1,
    const float* __restrict__ m2, const float* __restrict__ Wf,
    const float* __restrict__ bf, float* __restrict__ out){
  int tree = blockIdx.x; int t = threadIdx.x;
  float p0=0.f, p1=0.f;
  for (int k=t;k<512;k+=64){
    float x = (k<256) ? m1[tree*256+k] : m2[tree*256+(k-256)];
    p0 += x*Wf[k*2+0]; p1 += x*Wf[k*2+1];
  }
  #pragma unroll
  for (int off=32; off>0; off>>=1){
    p0 += __shfl_down(p0, off);
    p1 += __shfl_down(p1, off);
  }
  if (t==0){
    float l0 = p0+bf[0], l1 = p1+bf[1];
    l0 = (l0>0.f)?l0:0.01f*l0;
    l1 = (l1>0.f)?l1:0.01f*l1;
    float mx = fmaxf(l0,l1);
    float e0 = __expf(l0-mx), e1 = __expf(l1-mx);
    float inv = 1.0f/(e0+e1);
    out[tree*2+0] = e0*inv; out[tree*2+1] = e1*inv;
  }
}

extern "C" void kernel_launch(void* const* d_in, const int* in_sizes, int n_in,
                              void* d_out, int out_size, void* d_ws, size_t ws_size,
                              hipStream_t stream) {
  const int*   feat1 = (const int*)  d_in[0];
  const int*   feat2 = (const int*)  d_in[1];
  const float* emb1  = (const float*)d_in[2];
  const float* emb2  = (const float*)d_in[3];
  const float* Wiou1 = (const float*)d_in[4];
  const float* Wiou2 = (const float*)d_in[5];
  const float* Uiou1 = (const float*)d_in[6];
  const float* Uiou2 = (const float*)d_in[7];
  const float* UfW1  = (const float*)d_in[8];
  const float* Ufb1  = (const float*)d_in[9];
  const float* UfW2  = (const float*)d_in[10];
  const float* Ufb2  = (const float*)d_in[11];
  const float* biou1 = (const float*)d_in[12];
  const float* biou2 = (const float*)d_in[13];
  const float* Wf    = (const float*)d_in[14];
  const float* bfv   = (const float*)d_in[15];
  float* out = (float*)d_out;

  char* ws = (char*)d_ws;
  ushort* h1  = (ushort*)ws;  ws += (size_t)NN*256*2;   // 26.2 MB
  ushort* h2  = (ushort*)ws;  ws += (size_t)NN*256*2;
  ushort* c1  = (ushort*)ws;  ws += (size_t)NN*256*2;
  ushort* c2  = (ushort*)ws;  ws += (size_t)NN*256*2;
  ushort* E1  = (ushort*)ws;  ws += (size_t)VOCAB*256*2; // 5.12 MB
  ushort* E2  = (ushort*)ws;  ws += (size_t)VOCAB*256*2;
  ushort* Wt1 = (ushort*)ws;  ws += 768*256*2;
  ushort* Ut1 = (ushort*)ws;  ws += 768*256*2;
  ushort* Ft1 = (ushort*)ws;  ws += 256*256*2;
  ushort* Wt2 = (ushort*)ws;  ws += 768*256*2;
  ushort* Ut2 = (ushort*)ws;  ws += 768*256*2;
  ushort* Ft2 = (ushort*)ws;  ws += 256*256*2;
  float*  m1  = (float*)ws;   ws += NT*256*4;
  float*  m2  = (float*)ws;   ws += NT*256*4;

  convW_k<<<dim3(24, 8, 6), 256, 0, stream>>>(Wiou1, Uiou1, UfW1, Wiou2, Uiou2, UfW2,
                                              Wt1, Ut1, Ft1, Wt2, Ut2, Ft2);
  convE_k<<<dim3(2500, 2), 256, 0, stream>>>(emb1, emb2, E1, E2);
  embed_k<<<dim3(NL/16, 2), 256, 0, stream>>>(feat1, feat2, E1, E2, h1, h2);
  leaf_gemm<<<dim3(NL/64, 2), 1024, 0, stream>>>(Wt1, biou1, Wt2, biou2, h1, c1, h2, c2);

  const int lvlM[4]     = {9600, 2400, 600, 150};
  const int lvlShift[4] = {6, 4, 2, 0};
  const int lvlBase[4]  = {21, 5, 1, 0};
  for (int l=0;l<4;l++){
    int gx = (lvlM[l] + 15)/16;
    level_k<<<dim3(gx, 4, 2), 256, 0, stream>>>(Ut1, Ft1, Ufb1, biou1,
                                                Ut2, Ft2, Ufb2, biou2,
                                                h1, c1, h2, c2,
                                                lvlM[l], lvlShift[l], lvlBase[l]);
  }
  readout_k<<<dim3(NT, 2), 256, 0, stream>>>(h1, h2, m1, m2);
  final_k<<<NT, 64, 0, stream>>>(m1, m2, Wf, bfv, out);
}

// Round 4
// 380.846 us; speedup vs baseline: 3.0140x; 1.0669x over previous
//
#include <hip/hip_runtime.h>

#define NT 150      // trees
#define NPT 341     // nodes per tree
#define LEAF0 85    // first leaf local index
#define NL (NT*256) // 38400 leaves
#define NN (NT*NPT) // 51150 nodes
#define VOCAB 10000

typedef __attribute__((ext_vector_type(8))) short short8;
typedef __attribute__((ext_vector_type(4))) float floatx4;

__device__ __forceinline__ float sigf(float x){ return 1.0f/(1.0f+__expf(-x)); }
__device__ __forceinline__ float bf2f(ushort u){ union{unsigned i; float f;} v; v.i = ((unsigned)u)<<16; return v.f; }
__device__ __forceinline__ ushort f2bf(float x){ union{float f; unsigned i;} v; v.f = x; return (ushort)((v.i + 0x7fff + ((v.i>>16)&1))>>16); }

// ---------- weights transpose+convert: fp32 [256][N] -> bf16 [N][256] -------
__global__ __launch_bounds__(256) void convW_k(
    const float* __restrict__ W1, const float* __restrict__ U1, const float* __restrict__ F1,
    const float* __restrict__ W2, const float* __restrict__ U2, const float* __restrict__ F2,
    ushort* Wt1, ushort* Ut1, ushort* Ft1, ushort* Wt2, ushort* Ut2, ushort* Ft2){
  __shared__ float T[32][33];
  const float* src; ushort* dst; int N;
  switch (blockIdx.z){
    case 0: src=W1; dst=Wt1; N=768; break;
    case 1: src=U1; dst=Ut1; N=768; break;
    case 2: src=F1; dst=Ft1; N=256; break;
    case 3: src=W2; dst=Wt2; N=768; break;
    case 4: src=U2; dst=Ut2; N=768; break;
    default: src=F2; dst=Ft2; N=256; break;
  }
  int n0 = blockIdx.x*32; if (n0 >= N) return;
  int k0 = blockIdx.y*32;
  int nl = threadIdx.x & 31, kb = threadIdx.x >> 5;
  #pragma unroll
  for (int i=0;i<4;i++){ int kk = kb*4+i; T[kk][nl] = src[(size_t)(k0+kk)*N + n0 + nl]; }
  __syncthreads();
  #pragma unroll
  for (int i=0;i<4;i++){ int nn = kb*4+i; dst[(size_t)(n0+nn)*256 + k0 + nl] = f2bf(T[nl][nn]); }
}

// ---------- embedding tables fp32 -> bf16 (elementwise) ---------------------
__global__ __launch_bounds__(256) void convE_k(
    const float* __restrict__ e1, const float* __restrict__ e2,
    ushort* __restrict__ E1, ushort* __restrict__ E2){
  const float* s = blockIdx.y ? e2 : e1;
  ushort* d = blockIdx.y ? E2 : E1;
  size_t i = ((size_t)blockIdx.x*256 + threadIdx.x)*4;
  float4 v = *(const float4*)&s[i];
  d[i+0]=f2bf(v.x); d[i+1]=f2bf(v.y); d[i+2]=f2bf(v.z); d[i+3]=f2bf(v.w);
}

// ---------- embed: mean of 8 bf16 rows -> h leaf slots (bf16) ---------------
__global__ __launch_bounds__(256) void embed_k(
    const int* __restrict__ f1, const int* __restrict__ f2,
    const ushort* __restrict__ E1, const ushort* __restrict__ E2,
    ushort* __restrict__ h1, ushort* __restrict__ h2){
  int br = blockIdx.y;
  const int* feat = br ? f2 : f1;
  const ushort* E = br ? E2 : E1;
  ushort* h = br ? h2 : h1;
  int t = threadIdx.x;
  int leaf = blockIdx.x*16 + (t>>4);
  int seg = t & 15;
  int tree = leaf >> 8;
  size_t node = (size_t)tree*NPT + LEAF0 + (leaf & 255);
  const int* f = feat + node*8;
  float s[16];
  #pragma unroll
  for (int q=0;q<16;q++) s[q]=0.f;
  #pragma unroll
  for (int j=0;j<8;j++){
    const ushort* row = E + (size_t)f[j]*256 + seg*16;
    short8 a = *(const short8*)row;
    short8 b = *(const short8*)(row+8);
    #pragma unroll
    for (int q=0;q<8;q++){ s[q]+=bf2f((ushort)a[q]); s[8+q]+=bf2f((ushort)b[q]); }
  }
  short8 o1, o2;
  #pragma unroll
  for (int q=0;q<8;q++){ o1[q]=(short)f2bf(s[q]*0.125f); o2[q]=(short)f2bf(s[8+q]*0.125f); }
  ushort* dst = h + node*256 + seg*16;
  *(short8*)dst = o1; *(short8*)(dst+8) = o2;
}

// ---------- leaf GEMM: 64 leaves x all 768 outputs, 1024 threads ------------
__global__ __launch_bounds__(1024) void leaf_gemm(
    const ushort* __restrict__ Wt1, const float* __restrict__ b1,
    const ushort* __restrict__ Wt2, const float* __restrict__ b2,
    ushort* __restrict__ h1, ushort* __restrict__ c1,
    ushort* __restrict__ h2, ushort* __restrict__ c2){
  __shared__ __attribute__((aligned(16))) ushort As[8][64*40];
  int br = blockIdx.y;
  const ushort* Wt = br ? Wt2 : Wt1;
  const float* biou = br ? b2 : b1;
  ushort* h = br ? h2 : h1;
  ushort* c = br ? c2 : c1;
  int tid = threadIdx.x;
  int lane = tid & 63, wav = tid >> 6, quad = lane >> 4, l15 = lane & 15;
  int rowbase = blockIdx.x*64;

  { // stage full 64x256 A tile, one barrier
    int row = tid >> 4, seg = tid & 15;
    int leaf = rowbase + row;
    int tree = leaf >> 8;
    size_t node = (size_t)tree*NPT + LEAF0 + (leaf & 255);
    const ushort* src = h + node*256 + seg*16;
    short8 a = *(const short8*)src;
    short8 b = *(const short8*)(src+8);
    int cch = seg >> 1, off = (seg & 1)*16;
    *(short8*)&As[cch][row*40 + off]     = a;
    *(short8*)&As[cch][row*40 + off + 8] = b;
  }
  __syncthreads();

  floatx4 acc[3][4];
  #pragma unroll
  for (int g=0;g<3;g++)
    #pragma unroll
    for (int r=0;r<4;r++) acc[g][r] = (floatx4){0.f,0.f,0.f,0.f};

  const ushort* bp0 = Wt + (size_t)(0*256 + wav*16 + l15)*256 + quad*8;
  const ushort* bp1 = Wt + (size_t)(1*256 + wav*16 + l15)*256 + quad*8;
  const ushort* bp2 = Wt + (size_t)(2*256 + wav*16 + l15)*256 + quad*8;

  #pragma unroll
  for (int cch=0; cch<8; cch++){
    short8 b0 = *(const short8*)(bp0 + cch*32);
    short8 b1 = *(const short8*)(bp1 + cch*32);
    short8 b2 = *(const short8*)(bp2 + cch*32);
    #pragma unroll
    for (int r=0;r<4;r++){
      short8 a = *(const short8*)&As[cch][(16*r + l15)*40 + quad*8];
      acc[0][r] = __builtin_amdgcn_mfma_f32_16x16x32_bf16(a, b0, acc[0][r], 0,0,0);
      acc[1][r] = __builtin_amdgcn_mfma_f32_16x16x32_bf16(a, b1, acc[1][r], 0,0,0);
      acc[2][r] = __builtin_amdgcn_mfma_f32_16x16x32_bf16(a, b2, acc[2][r], 0,0,0);
    }
  }
  int hc = wav*16 + l15;
  float bi = biou[hc], bo = biou[256+hc], bu = biou[512+hc];
  #pragma unroll
  for (int r=0;r<4;r++){
    #pragma unroll
    for (int reg=0;reg<4;reg++){
      int leaf = rowbase + 16*r + quad*4 + reg;
      int tree = leaf >> 8;
      size_t node = (size_t)tree*NPT + LEAF0 + (leaf & 255);
      float iv = acc[0][r][reg] + bi;
      float ov = acc[1][r][reg] + bo;
      float uv = acc[2][r][reg] + bu;
      float cc = sigf(iv)*tanhf(uv);
      float hh = sigf(ov)*tanhf(cc);
      h[node*256 + hc] = f2bf(hh);
      c[node*256 + hc] = f2bf(cc);
    }
  }
}

// ---------- internal level: per-child MFMA for all 4 matrices ---------------
// iou(node) = sum over children of h_child @ U  (== h_tild @ U, fp32 acc)
// Lane-local: 4 acc regs = 4 children of one node -> register-only reduction.
// grid (ceil(M/16), 4 colgroups, 2 branches), 1 barrier, LDS 40KB.
__global__ __launch_bounds__(256) void level_k(
    const ushort* __restrict__ Ut1, const ushort* __restrict__ Ft1,
    const float* __restrict__ Ufb1, const float* __restrict__ bi1,
    const ushort* __restrict__ Ut2, const ushort* __restrict__ Ft2,
    const float* __restrict__ Ufb2, const float* __restrict__ bi2,
    ushort* __restrict__ h1, ushort* __restrict__ c1,
    ushort* __restrict__ h2, ushort* __restrict__ c2,
    int M, int shift, int base){
  __shared__ __attribute__((aligned(16))) ushort Ch[8][64*40];
  int br = blockIdx.z;
  const ushort* Ut = br ? Ut2 : Ut1;
  const ushort* Ft = br ? Ft2 : Ft1;
  const float* Ufb = br ? Ufb2 : Ufb1;
  const float* biou = br ? bi2 : bi1;
  ushort* h = br ? h2 : h1;
  ushort* c = br ? c2 : c1;
  int tid = threadIdx.x;
  int lane = tid & 63, wav = tid >> 6, quad = lane >> 4, l15 = lane & 15;
  int m0 = blockIdx.x*16, cb = blockIdx.y;
  int mask = (1<<shift)-1;

  { // stage 64 children rows x 256 k (one barrier)
    int cl = tid >> 2, q4 = tid & 3;
    int sm = m0 + (cl >> 2); if (sm > M-1) sm = M-1;
    int stree = sm >> shift, sloc = base + (sm & mask);
    const ushort* sgp = h + ((size_t)stree*NPT + 4*sloc + 1 + (cl & 3))*256 + q4*8;
    #pragma unroll
    for (int cc=0;cc<8;cc++)
      *(short8*)&Ch[cc][cl*40 + q4*8] = *(const short8*)(sgp + cc*32);
  }
  __syncthreads();

  int col = cb*64 + wav*16 + l15;
  const ushort* bfp = Ft + (size_t)col*256 + quad*8;
  const ushort* bp0 = Ut + (size_t)(0*256 + col)*256 + quad*8;
  const ushort* bp1 = Ut + (size_t)(256 + col)*256 + quad*8;
  const ushort* bp2 = Ut + (size_t)(512 + col)*256 + quad*8;

  floatx4 af[4], ai[4], ao[4], au[4];
  #pragma unroll
  for (int r=0;r<4;r++){
    af[r] = (floatx4){0.f,0.f,0.f,0.f}; ai[r] = (floatx4){0.f,0.f,0.f,0.f};
    ao[r] = (floatx4){0.f,0.f,0.f,0.f}; au[r] = (floatx4){0.f,0.f,0.f,0.f};
  }

  #pragma unroll
  for (int cc=0; cc<8; cc++){
    short8 Bf = *(const short8*)(bfp + cc*32);
    short8 Bi = *(const short8*)(bp0 + cc*32);
    short8 Bo = *(const short8*)(bp1 + cc*32);
    short8 Bu = *(const short8*)(bp2 + cc*32);
    #pragma unroll
    for (int r=0;r<4;r++){
      short8 a = *(const short8*)&Ch[cc][(16*r + l15)*40 + quad*8];
      af[r] = __builtin_amdgcn_mfma_f32_16x16x32_bf16(a, Bf, af[r], 0,0,0);
      ai[r] = __builtin_amdgcn_mfma_f32_16x16x32_bf16(a, Bi, ai[r], 0,0,0);
      ao[r] = __builtin_amdgcn_mfma_f32_16x16x32_bf16(a, Bo, ao[r], 0,0,0);
      au[r] = __builtin_amdgcn_mfma_f32_16x16x32_bf16(a, Bu, au[r], 0,0,0);
    }
  }

  float ufb = Ufb[col];
  float bI = biou[col], bO = biou[256+col], bU = biou[512+col];
  #pragma unroll
  for (int r=0;r<4;r++){
    int m = m0 + 4*r + quad;
    int mm = m < M ? m : M-1;
    int tree = mm >> shift, loc = base + (mm & mask);
    size_t ch0 = ((size_t)tree*NPT + 4*loc + 1)*256 + col;
    float cs = 0.f;
    #pragma unroll
    for (int reg=0;reg<4;reg++)
      cs += sigf(af[r][reg] + ufb) * bf2f(c[ch0 + (size_t)reg*256]);
    float iv = ai[r][0]+ai[r][1]+ai[r][2]+ai[r][3] + bI;
    float ov = ao[r][0]+ao[r][1]+ao[r][2]+ao[r][3] + bO;
    float uv = au[r][0]+au[r][1]+au[r][2]+au[r][3] + bU;
    float cn = sigf(iv)*tanhf(uv) + cs;
    float hn = sigf(ov)*tanhf(cn);
    if (m < M){
      size_t off = ((size_t)tree*NPT + loc)*256 + col;
      h[off] = f2bf(hn);
      c[off] = f2bf(cn);
    }
  }
}

// ---------- readout partials: sum h over ~85 nodes per (tree,part) ----------
__global__ __launch_bounds__(256) void readout_k(
    const ushort* __restrict__ h1, const ushort* __restrict__ h2,
    float* __restrict__ mp1, float* __restrict__ mp2){
  int br = blockIdx.z, part = blockIdx.y, tree = blockIdx.x;
  const ushort* h = br ? h2 : h1;
  float* mp = br ? mp2 : mp1;
  int t = threadIdx.x;
  int start = part*85;
  int cnt = (part==3) ? 86 : 85;
  const ushort* hp = h + ((size_t)tree*NPT + start)*256 + t;
  float s0=0.f,s1=0.f,s2=0.f,s3=0.f;
  int i = 0;
  for (; i+4<=cnt; i+=4){
    s0 += bf2f(hp[(size_t)(i+0)*256]); s1 += bf2f(hp[(size_t)(i+1)*256]);
    s2 += bf2f(hp[(size_t)(i+2)*256]); s3 += bf2f(hp[(size_t)(i+3)*256]);
  }
  for (; i<cnt; i++) s0 += bf2f(hp[(size_t)i*256]);
  mp[((size_t)tree*4 + part)*256 + t] = s0+s1+s2+s3;
}

// ---------- final: mean->relu->concat@Wf->leaky_relu->softmax ---------------
__global__ __launch_bounds__(64) void final_k(const float* __restrict__ mp1,
    const float* __restrict__ mp2, const float* __restrict__ Wf,
    const float* __restrict__ bf, float* __restrict__ out){
  int tree = blockIdx.x; int t = threadIdx.x;
  float p0=0.f, p1=0.f;
  for (int k=t;k<512;k+=64){
    const float* mp = (k<256) ? mp1 : mp2;
    int kk = k & 255;
    size_t b0 = ((size_t)tree*4)*256 + kk;
    float s = mp[b0] + mp[b0+256] + mp[b0+512] + mp[b0+768];
    float x = fmaxf(s*(1.0f/341.0f), 0.f);
    p0 += x*Wf[k*2+0]; p1 += x*Wf[k*2+1];
  }
  #pragma unroll
  for (int off=32; off>0; off>>=1){
    p0 += __shfl_down(p0, off);
    p1 += __shfl_down(p1, off);
  }
  if (t==0){
    float l0 = p0+bf[0], l1 = p1+bf[1];
    l0 = (l0>0.f)?l0:0.01f*l0;
    l1 = (l1>0.f)?l1:0.01f*l1;
    float mx = fmaxf(l0,l1);
    float e0 = __expf(l0-mx), e1 = __expf(l1-mx);
    float inv = 1.0f/(e0+e1);
    out[tree*2+0] = e0*inv; out[tree*2+1] = e1*inv;
  }
}

extern "C" void kernel_launch(void* const* d_in, const int* in_sizes, int n_in,
                              void* d_out, int out_size, void* d_ws, size_t ws_size,
                              hipStream_t stream) {
  const int*   feat1 = (const int*)  d_in[0];
  const int*   feat2 = (const int*)  d_in[1];
  const float* emb1  = (const float*)d_in[2];
  const float* emb2  = (const float*)d_in[3];
  const float* Wiou1 = (const float*)d_in[4];
  const float* Wiou2 = (const float*)d_in[5];
  const float* Uiou1 = (const float*)d_in[6];
  const float* Uiou2 = (const float*)d_in[7];
  const float* UfW1  = (const float*)d_in[8];
  const float* Ufb1  = (const float*)d_in[9];
  const float* UfW2  = (const float*)d_in[10];
  const float* Ufb2  = (const float*)d_in[11];
  const float* biou1 = (const float*)d_in[12];
  const float* biou2 = (const float*)d_in[13];
  const float* Wf    = (const float*)d_in[14];
  const float* bfv   = (const float*)d_in[15];
  float* out = (float*)d_out;

  char* ws = (char*)d_ws;
  ushort* h1  = (ushort*)ws;  ws += (size_t)NN*256*2;   // 26.2 MB
  ushort* h2  = (ushort*)ws;  ws += (size_t)NN*256*2;
  ushort* c1  = (ushort*)ws;  ws += (size_t)NN*256*2;
  ushort* c2  = (ushort*)ws;  ws += (size_t)NN*256*2;
  ushort* E1  = (ushort*)ws;  ws += (size_t)VOCAB*256*2; // 5.12 MB
  ushort* E2  = (ushort*)ws;  ws += (size_t)VOCAB*256*2;
  ushort* Wt1 = (ushort*)ws;  ws += 768*256*2;
  ushort* Ut1 = (ushort*)ws;  ws += 768*256*2;
  ushort* Ft1 = (ushort*)ws;  ws += 256*256*2;
  ushort* Wt2 = (ushort*)ws;  ws += 768*256*2;
  ushort* Ut2 = (ushort*)ws;  ws += 768*256*2;
  ushort* Ft2 = (ushort*)ws;  ws += 256*256*2;
  float*  mp1 = (float*)ws;   ws += (size_t)NT*4*256*4;
  float*  mp2 = (float*)ws;   ws += (size_t)NT*4*256*4;

  convW_k<<<dim3(24, 8, 6), 256, 0, stream>>>(Wiou1, Uiou1, UfW1, Wiou2, Uiou2, UfW2,
                                              Wt1, Ut1, Ft1, Wt2, Ut2, Ft2);
  convE_k<<<dim3(2500, 2), 256, 0, stream>>>(emb1, emb2, E1, E2);
  embed_k<<<dim3(NL/16, 2), 256, 0, stream>>>(feat1, feat2, E1, E2, h1, h2);
  leaf_gemm<<<dim3(NL/64, 2), 1024, 0, stream>>>(Wt1, biou1, Wt2, biou2, h1, c1, h2, c2);

  const int lvlM[4]     = {9600, 2400, 600, 150};
  const int lvlShift[4] = {6, 4, 2, 0};
  const int lvlBase[4]  = {21, 5, 1, 0};
  for (int l=0;l<4;l++){
    int gx = (lvlM[l] + 15)/16;
    level_k<<<dim3(gx, 4, 2), 256, 0, stream>>>(Ut1, Ft1, Ufb1, biou1,
                                                Ut2, Ft2, Ufb2, biou2,
                                                h1, c1, h2, c2,
                                                lvlM[l], lvlShift[l], lvlBase[l]);
  }
  readout_k<<<dim3(NT, 4, 2), 256, 0, stream>>>(h1, h2, mp1, mp2);
  final_k<<<NT, 64, 0, stream>>>(mp1, mp2, Wf, bfv, out);
}